// Round 8
// baseline (253.810 us; speedup 1.0000x reference)
//
#include <hip/hip_runtime.h>

// Mamba selective scan: BATCH=2, DIM=768, L=2048, N=16, fp32.
// R8: diagnostic + fix round.
//  - pass2 rewritten: no in-place alias (writes x_init to separate hI),
//    16-deep explicit load batching, 192x128 grid.
//  - ALL kernels internally repeat REP=5x (idempotent; pointers offset by
//    rep*z0 with z0=0 at runtime to defeat CSE) so each dispatch exceeds the
//    42us poison-fill cutoff and appears in rocprof top-5 WITH counters.
//    Divide observed durations by 5. Next round strips REP.

#define LOG2E 1.4426950408889634f
#define LN2   0.6931471805599453f

constexpr int BATCH = 2, DIM = 768, L = 2048, N = 16;
constexpr int NC = 128, LC = 16;       // chunks, steps per chunk
constexpr int DG = DIM / 64;           // 12 d-groups
constexpr int CPB = 4;                 // chunks per block (1 per wave)
constexpr int CG = NC / CPB;           // 32 chunk-groups
constexpr int NBLK = BATCH * DG * CG;  // 768 blocks
constexpr int NCOMB = BATCH * DIM * N; // 24576 combine threads
constexpr int REP = 5;                 // diagnostic repeat factor
static_assert(NC * LC == L, "chunking must cover L");

__device__ __forceinline__ float fexp2(float x) { return __builtin_amdgcn_exp2f(x); }
__device__ __forceinline__ float softplus(float v) {
  float s = LN2 * __log2f(1.0f + fexp2(v * LOG2E));
  return (v > 20.0f) ? v : s;
}
__device__ __forceinline__ float silu(float v) { return v / (1.0f + fexp2(-v * LOG2E)); }

// ---------------- pass 1 ----------------
__global__ __launch_bounds__(256, 4) void k_pass1(
    const float* __restrict__ u0, const float* __restrict__ delta0,
    const float* __restrict__ A, const float* __restrict__ dbias,
    const float* __restrict__ Bg0, float* __restrict__ h, float* __restrict__ S,
    int z0)
{
  __shared__ float ds_[64][68];
  __shared__ float us[64][68];
  __shared__ float Bsr[64][20];

  const int bid = blockIdx.x, t = threadIdx.x;
  const int cgi = bid & 31;
  const int dgb = bid >> 5;
  const int dg = dgb % DG;
  const int b = dgb / DG;
  const int d0 = dg * 64, l0 = cgi * 64;

  const int w = t >> 6, lane = t & 63;
  const int c = cgi * CPB + w;
  const int d = d0 + lane;

  float A2[N];
#pragma unroll
  for (int q = 0; q < 4; q++) {
    float4 av = *(const float4*)(A + d * N + q * 4);
    A2[q*4+0] = av.x * LOG2E; A2[q*4+1] = av.y * LOG2E;
    A2[q*4+2] = av.z * LOG2E; A2[q*4+3] = av.w * LOG2E;
  }
  const float bias = dbias[d];
  const int row16 = t >> 4;
  const int col4 = (t & 15) * 4;

  for (int rep = 0; rep < REP; ++rep) {
    const float* delta = delta0 + (long)rep * z0;
    const float* uptr  = u0 + (long)rep * z0;
    const float* Bg    = Bg0 + (long)rep * z0;

#pragma unroll
    for (int rr = 0; rr < 4; rr++) {
      int row = row16 + rr * 16;
      long gof = ((long)(b * DIM + d0 + row)) * L + l0 + col4;
      *(float4*)&ds_[row][col4] = *(const float4*)(delta + gof);
      *(float4*)&us[row][col4]  = *(const float4*)(uptr + gof);
    }
    long bof = ((long)(b * N + row16)) * L + l0 + col4;
    float4 v = *(const float4*)(Bg + bof);
    Bsr[col4 + 0][row16] = v.x;
    Bsr[col4 + 1][row16] = v.y;
    Bsr[col4 + 2][row16] = v.z;
    Bsr[col4 + 3][row16] = v.w;

    __syncthreads();

    float sp[LC], uu[LC], Ssum = 0.f;
#pragma unroll
    for (int q = 0; q < 4; q++) {
      float4 dv = *(const float4*)&ds_[lane][w * LC + q * 4];
      float4 uv = *(const float4*)&us[lane][w * LC + q * 4];
      sp[q*4+0] = softplus(dv.x + bias); uu[q*4+0] = uv.x;
      sp[q*4+1] = softplus(dv.y + bias); uu[q*4+1] = uv.y;
      sp[q*4+2] = softplus(dv.z + bias); uu[q*4+2] = uv.z;
      sp[q*4+3] = softplus(dv.w + bias); uu[q*4+3] = uv.w;
    }
#pragma unroll
    for (int j = 0; j < LC; j++) Ssum += sp[j];

    float x[N];
#pragma unroll
    for (int n = 0; n < N; n++) x[n] = 0.f;
#pragma unroll
    for (int j = 0; j < LC; j++) {
      const int row = w * LC + j;
      float bb[16];
#pragma unroll
      for (int q = 0; q < 4; q++) {
        float4 bv = *(const float4*)&Bsr[row][q * 4];
        bb[q*4+0] = bv.x; bb[q*4+1] = bv.y; bb[q*4+2] = bv.z; bb[q*4+3] = bv.w;
      }
      float du = sp[j] * uu[j];
#pragma unroll
      for (int n = 0; n < N; n++) {
        float a = fexp2(sp[j] * A2[n]);
        x[n] = a * x[n] + du * bb[n];
      }
    }

    const long hb = ((long)(b * NC + c)) * N * DIM + d;   // [b][c][n][d]
#pragma unroll
    for (int n = 0; n < N; n++) h[hb + (long)n * DIM] = x[n];
    S[(b * NC + c) * DIM + d] = Ssum;

    __syncthreads();   // before restage next rep
  }
}

// ---------------- pass 2: combine, no alias, batched loads ----------------
__global__ __launch_bounds__(128) void k_pass2(
    const float* __restrict__ h0, const float* __restrict__ S0,
    const float* __restrict__ A, float* __restrict__ hI, int z0)
{
  int g = blockIdx.x * 128 + threadIdx.x;   // g = (bb*16 + n)*768 + dd
  int dd = g % DIM;
  int r = g / DIM;
  int n = r & 15;
  int bb = r >> 4;
  const float a2 = A[dd * N + n] * LOG2E;
  const long step = (long)N * DIM;
  const long base0 = (((long)(bb * NC)) * N + n) * DIM + dd;
  const long sbase = (long)(bb * NC) * DIM + dd;

  for (int rep = 0; rep < REP; ++rep) {
    const float* h = h0 + (long)rep * z0;
    const float* Sp = S0 + (long)rep * z0;
    float x = 0.f;
    for (int cb = 0; cb < NC / 16; cb++) {
      float hc[16], Sc[16];
#pragma unroll
      for (int k = 0; k < 16; k++) {
        hc[k] = h[base0 + (long)(cb * 16 + k) * step];
        Sc[k] = Sp[sbase + (long)(cb * 16 + k) * DIM];
      }
#pragma unroll
      for (int k = 0; k < 16; k++) {
        hI[base0 + (long)(cb * 16 + k) * step] = x;   // x_init for chunk
        x = fexp2(Sc[k] * a2) * x + hc[k];
      }
    }
  }
}

// ---------------- pass 3 ----------------
__global__ __launch_bounds__(256, 3) void k_pass3(
    const float* __restrict__ u0, const float* __restrict__ delta0,
    const float* __restrict__ A, const float* __restrict__ dbias,
    const float* __restrict__ Bg0, const float* __restrict__ Cg0,
    const float* __restrict__ Dv, const float* __restrict__ z,
    const float* __restrict__ xinit0, float* __restrict__ out, int z0)
{
  __shared__ float ds_[64][68];   // delta slab, reused as y slab
  __shared__ float us[64][68];
  __shared__ float Bsr[64][20];
  __shared__ float Csr[64][20];

  const int bid = blockIdx.x, t = threadIdx.x;
  const int cgi = bid & 31;
  const int dgb = bid >> 5;
  const int dg = dgb % DG;
  const int b = dgb / DG;
  const int d0 = dg * 64, l0 = cgi * 64;

  const int w = t >> 6, lane = t & 63;
  const int c = cgi * CPB + w;
  const int d = d0 + lane;

  float A2[N];
#pragma unroll
  for (int q = 0; q < 4; q++) {
    float4 av = *(const float4*)(A + d * N + q * 4);
    A2[q*4+0] = av.x * LOG2E; A2[q*4+1] = av.y * LOG2E;
    A2[q*4+2] = av.z * LOG2E; A2[q*4+3] = av.w * LOG2E;
  }
  const float bias = dbias[d];
  const int row16 = t >> 4;
  const int col4 = (t & 15) * 4;

  for (int rep = 0; rep < REP; ++rep) {
    const float* delta = delta0 + (long)rep * z0;
    const float* uptr  = u0 + (long)rep * z0;
    const float* Bg    = Bg0 + (long)rep * z0;
    const float* Cg    = Cg0 + (long)rep * z0;
    const float* xinit = xinit0 + (long)rep * z0;

#pragma unroll
    for (int rr = 0; rr < 4; rr++) {
      int row = row16 + rr * 16;
      long gof = ((long)(b * DIM + d0 + row)) * L + l0 + col4;
      *(float4*)&ds_[row][col4] = *(const float4*)(delta + gof);
      *(float4*)&us[row][col4]  = *(const float4*)(uptr + gof);
    }
    long bof = ((long)(b * N + row16)) * L + l0 + col4;
    float4 v = *(const float4*)(Bg + bof);
    Bsr[col4 + 0][row16] = v.x;
    Bsr[col4 + 1][row16] = v.y;
    Bsr[col4 + 2][row16] = v.z;
    Bsr[col4 + 3][row16] = v.w;
    float4 wv = *(const float4*)(Cg + bof);
    Csr[col4 + 0][row16] = wv.x;
    Csr[col4 + 1][row16] = wv.y;
    Csr[col4 + 2][row16] = wv.z;
    Csr[col4 + 3][row16] = wv.w;

    // x_init: [b][c][n][d] coalesced
    const long hb = ((long)(b * NC + c)) * N * DIM + d;
    float x[N];
#pragma unroll
    for (int n = 0; n < N; n++) x[n] = xinit[hb + (long)n * DIM];

    __syncthreads();

    float sp[LC], uu[LC];
#pragma unroll
    for (int q = 0; q < 4; q++) {
      float4 dv = *(const float4*)&ds_[lane][w * LC + q * 4];
      float4 uv = *(const float4*)&us[lane][w * LC + q * 4];
      sp[q*4+0] = softplus(dv.x + bias); uu[q*4+0] = uv.x;
      sp[q*4+1] = softplus(dv.y + bias); uu[q*4+1] = uv.y;
      sp[q*4+2] = softplus(dv.z + bias); uu[q*4+2] = uv.z;
      sp[q*4+3] = softplus(dv.w + bias); uu[q*4+3] = uv.w;
    }

    __syncthreads();   // done reading ds_ as delta; rewrite as y

    float y[LC];
#pragma unroll
    for (int j = 0; j < LC; j++) {
      const int row = w * LC + j;
      float bb[16], ccv[16];
#pragma unroll
      for (int q = 0; q < 4; q++) {
        float4 bv = *(const float4*)&Bsr[row][q * 4];
        float4 cv = *(const float4*)&Csr[row][q * 4];
        bb[q*4+0] = bv.x; bb[q*4+1] = bv.y; bb[q*4+2] = bv.z; bb[q*4+3] = bv.w;
        ccv[q*4+0] = cv.x; ccv[q*4+1] = cv.y; ccv[q*4+2] = cv.z; ccv[q*4+3] = cv.w;
      }
      float du = sp[j] * uu[j];
      float acc = 0.f;
#pragma unroll
      for (int n = 0; n < N; n++) {
        float a = fexp2(sp[j] * A2[n]);
        x[n] = a * x[n] + du * bb[n];
        acc += x[n] * ccv[n];
      }
      y[j] = acc;
    }
#pragma unroll
    for (int q = 0; q < 4; q++) {
      float4 v2; v2.x = y[q*4+0]; v2.y = y[q*4+1]; v2.z = y[q*4+2]; v2.w = y[q*4+3];
      *(float4*)&ds_[lane][w * LC + q * 4] = v2;
    }

    __syncthreads();

    // coalesced fused epilogue: out = (y + u*D) * silu(z)
#pragma unroll
    for (int rr = 0; rr < 4; rr++) {
      int row = row16 + rr * 16;
      long gof = ((long)(b * DIM + d0 + row)) * L + l0 + col4;
      float4 zv = *(const float4*)(z + gof);
      float4 yv = *(const float4*)&ds_[row][col4];
      float4 uv = *(const float4*)&us[row][col4];
      float Dd2 = Dv[d0 + row];
      float4 ov;
      ov.x = (yv.x + uv.x * Dd2) * silu(zv.x);
      ov.y = (yv.y + uv.y * Dd2) * silu(zv.y);
      ov.z = (yv.z + uv.z * Dd2) * silu(zv.z);
      ov.w = (yv.w + uv.w * Dd2) * silu(zv.w);
      *(float4*)(out + gof) = ov;
    }

    __syncthreads();   // before restage next rep
  }
}

// ---------------- fallback (ws too small) ----------------
__global__ __launch_bounds__(256) void k_simple(
    const float* __restrict__ u, const float* __restrict__ delta,
    const float* __restrict__ A, const float* __restrict__ dbias,
    const float* __restrict__ Bm, const float* __restrict__ Cm,
    const float* __restrict__ Dv, const float* __restrict__ z,
    float* __restrict__ out) {
  int t = blockIdx.x * 256 + threadIdx.x;
  int n = t % N;
  int bd = t / N;
  int d = bd % DIM;
  int b = bd / DIM;
  float A2 = A[d * N + n] * LOG2E;
  float bias = dbias[d];
  float Dd = Dv[d];
  const float* Bp = Bm + ((long)b * N + n) * L;
  const float* Cp = Cm + ((long)b * N + n) * L;
  long base = (long)bd * L;
  float x = 0.0f;
  for (int l = 0; l < L; l++) {
    float dv = delta[base + l];
    float uv = u[base + l];
    float sp = softplus(dv + bias);
    float a = fexp2(sp * A2);
    x = a * x + sp * uv * Bp[l];
    float y = x * Cp[l];
#pragma unroll
    for (int off = 8; off; off >>= 1) y += __shfl_xor(y, off, 16);
    if (n == 0) {
      float zv = z[base + l];
      out[base + l] = (y + uv * Dd) * silu(zv);
    }
  }
}

extern "C" void kernel_launch(void* const* d_in, const int* in_sizes, int n_in,
                              void* d_out, int out_size, void* d_ws, size_t ws_size,
                              hipStream_t stream) {
  const float* u     = (const float*)d_in[0];
  const float* delta = (const float*)d_in[1];
  const float* A     = (const float*)d_in[2];
  const float* Bm    = (const float*)d_in[3];
  const float* Cm    = (const float*)d_in[4];
  const float* Dv    = (const float*)d_in[5];
  const float* z     = (const float*)d_in[6];
  const float* dbias = (const float*)d_in[7];
  float* out = (float*)d_out;

  const size_t hp  = (size_t)BATCH * NC * DIM * N;  // 3.15M floats
  const size_t spn = (size_t)BATCH * NC * DIM;      // 196K floats
  const size_t need = (2 * hp + spn) * sizeof(float);

  if (ws_size < need) {
    k_simple<<<(BATCH * DIM * N) / 256, 256, 0, stream>>>(u, delta, A, dbias, Bm, Cm, Dv, z, out);
    return;
  }

  float* h  = (float*)d_ws;
  float* S  = h + hp;
  float* hI = S + spn;
  int z0 = 0;

  k_pass1<<<NBLK, 256, 0, stream>>>(u, delta, A, dbias, Bm, h, S, z0);
  k_pass2<<<NCOMB / 128, 128, 0, stream>>>(h, S, A, hI, z0);
  k_pass3<<<NBLK, 256, 0, stream>>>(u, delta, A, dbias, Bm, Cm, Dv, z, hI, out, z0);
}

// Round 9
// 132.622 us; speedup vs baseline: 1.9138x; 1.9138x over previous
//
#include <hip/hip_runtime.h>

// Mamba selective scan: BATCH=2, DIM=768, L=2048, N=16, fp32.
// R9: occupancy + instruction-count round (R8 showed pass3 VALU-bound at 25% occ).
//  - ONE time-shared LDS slab (delta -> u -> y) instead of two: p1 22.5KB
//    (7 blk/CU), p3 27.6KB (5 blk/CU). Epilogue re-reads u from global (L2-hot).
//  - h/hI layout [b][c][d][n]: p1 store / p3 load = 4x float4 contiguous.
//  - pass2: non-aliased hI output, 16-deep batched loads (R8 fix, kept).

#define LOG2E 1.4426950408889634f
#define LN2   0.6931471805599453f

constexpr int BATCH = 2, DIM = 768, L = 2048, N = 16;
constexpr int NC = 128, LC = 16;       // chunks, steps per chunk
constexpr int DG = DIM / 64;           // 12 d-groups
constexpr int CPB = 4;                 // chunks per block (1 per wave)
constexpr int CG = NC / CPB;           // 32 chunk-groups
constexpr int NBLK = BATCH * DG * CG;  // 768 blocks
constexpr int NCOMB = BATCH * DIM * N; // 24576 combine threads
static_assert(NC * LC == L, "chunking must cover L");

__device__ __forceinline__ float fexp2(float x) { return __builtin_amdgcn_exp2f(x); }
__device__ __forceinline__ float softplus(float v) {
  float s = LN2 * __log2f(1.0f + fexp2(v * LOG2E));
  return (v > 20.0f) ? v : s;
}
__device__ __forceinline__ float silu(float v) { return v / (1.0f + fexp2(-v * LOG2E)); }

// ---------------- pass 1 ----------------
__global__ __launch_bounds__(256, 6) void k_pass1(
    const float* __restrict__ u, const float* __restrict__ delta,
    const float* __restrict__ A, const float* __restrict__ dbias,
    const float* __restrict__ Bg, float* __restrict__ h, float* __restrict__ S)
{
  __shared__ float slab[64][68];   // time-shared: delta, then u
  __shared__ float Bsr[64][20];    // [l][n] transposed

  const int bid = blockIdx.x, t = threadIdx.x;
  const int cgi = bid & 31;
  const int dgb = bid >> 5;
  const int dg = dgb % DG;
  const int b = dgb / DG;
  const int d0 = dg * 64, l0 = cgi * 64;

  const int w = t >> 6, lane = t & 63;
  const int c = cgi * CPB + w;
  const int d = d0 + lane;
  const int row16 = t >> 4;
  const int col4 = (t & 15) * 4;

  // stage delta + B (coalesced)
#pragma unroll
  for (int rr = 0; rr < 4; rr++) {
    int row = row16 + rr * 16;
    long gof = ((long)(b * DIM + d0 + row)) * L + l0 + col4;
    *(float4*)&slab[row][col4] = *(const float4*)(delta + gof);
  }
  {
    long bof = ((long)(b * N + row16)) * L + l0 + col4;
    float4 v = *(const float4*)(Bg + bof);
    Bsr[col4 + 0][row16] = v.x;
    Bsr[col4 + 1][row16] = v.y;
    Bsr[col4 + 2][row16] = v.z;
    Bsr[col4 + 3][row16] = v.w;
  }

  float A2[N];
#pragma unroll
  for (int q = 0; q < 4; q++) {
    float4 av = *(const float4*)(A + d * N + q * 4);
    A2[q*4+0] = av.x * LOG2E; A2[q*4+1] = av.y * LOG2E;
    A2[q*4+2] = av.z * LOG2E; A2[q*4+3] = av.w * LOG2E;
  }
  const float bias = dbias[d];

  __syncthreads();

  float sp[LC], Ssum = 0.f;
#pragma unroll
  for (int q = 0; q < 4; q++) {
    float4 dv = *(const float4*)&slab[lane][w * LC + q * 4];
    sp[q*4+0] = softplus(dv.x + bias);
    sp[q*4+1] = softplus(dv.y + bias);
    sp[q*4+2] = softplus(dv.z + bias);
    sp[q*4+3] = softplus(dv.w + bias);
  }
#pragma unroll
  for (int j = 0; j < LC; j++) Ssum += sp[j];

  __syncthreads();   // done reading slab-as-delta

  // restage u into the same slab
#pragma unroll
  for (int rr = 0; rr < 4; rr++) {
    int row = row16 + rr * 16;
    long gof = ((long)(b * DIM + d0 + row)) * L + l0 + col4;
    *(float4*)&slab[row][col4] = *(const float4*)(u + gof);
  }

  __syncthreads();

  float uu[LC];
#pragma unroll
  for (int q = 0; q < 4; q++) {
    float4 uv = *(const float4*)&slab[lane][w * LC + q * 4];
    uu[q*4+0] = uv.x; uu[q*4+1] = uv.y; uu[q*4+2] = uv.z; uu[q*4+3] = uv.w;
  }

  float x[N];
#pragma unroll
  for (int n = 0; n < N; n++) x[n] = 0.f;
#pragma unroll
  for (int j = 0; j < LC; j++) {
    const int row = w * LC + j;
    float bb[16];
#pragma unroll
    for (int q = 0; q < 4; q++) {
      float4 bv = *(const float4*)&Bsr[row][q * 4];
      bb[q*4+0] = bv.x; bb[q*4+1] = bv.y; bb[q*4+2] = bv.z; bb[q*4+3] = bv.w;
    }
    float du = sp[j] * uu[j];
#pragma unroll
    for (int n = 0; n < N; n++) {
      float a = fexp2(sp[j] * A2[n]);
      x[n] = a * x[n] + du * bb[n];
    }
  }

  // h layout [b][c][d][n]: 4x float4 contiguous per lane
  const long hb = (((long)(b * NC + c)) * DIM + d) * N;
#pragma unroll
  for (int q = 0; q < 4; q++) {
    float4 v; v.x = x[q*4+0]; v.y = x[q*4+1]; v.z = x[q*4+2]; v.w = x[q*4+3];
    *(float4*)(h + hb + q * 4) = v;
  }
  S[(b * NC + c) * DIM + d] = Ssum;
}

// ---------------- pass 2: combine, no alias, batched ----------------
__global__ __launch_bounds__(128) void k_pass2(
    const float* __restrict__ h, const float* __restrict__ S,
    const float* __restrict__ A, float* __restrict__ hI)
{
  int g = blockIdx.x * 128 + threadIdx.x;   // g = (bb*768 + dd)*16 + n
  int n = g & 15;
  int r = g >> 4;
  int dd = r % DIM;
  int bb = r / DIM;
  const float a2 = A[dd * N + n] * LOG2E;
  const long step = (long)DIM * N;
  const long base0 = (((long)bb * NC) * DIM + dd) * N + n;
  const long sbase = (long)(bb * NC) * DIM + dd;

  float x = 0.f;
  for (int cb = 0; cb < NC / 16; cb++) {
    float hc[16], Sc[16];
#pragma unroll
    for (int k = 0; k < 16; k++) {
      hc[k] = h[base0 + (long)(cb * 16 + k) * step];
      Sc[k] = S[sbase + (long)(cb * 16 + k) * DIM];
    }
#pragma unroll
    for (int k = 0; k < 16; k++) {
      hI[base0 + (long)(cb * 16 + k) * step] = x;
      x = fexp2(Sc[k] * a2) * x + hc[k];
    }
  }
}

// ---------------- pass 3 ----------------
__global__ __launch_bounds__(256, 5) void k_pass3(
    const float* __restrict__ u, const float* __restrict__ delta,
    const float* __restrict__ A, const float* __restrict__ dbias,
    const float* __restrict__ Bg, const float* __restrict__ Cg,
    const float* __restrict__ Dv, const float* __restrict__ z,
    const float* __restrict__ xinit, float* __restrict__ out)
{
  __shared__ float slab[64][68];   // time-shared: delta, then u, then y
  __shared__ float Bsr[64][20];
  __shared__ float Csr[64][20];

  const int bid = blockIdx.x, t = threadIdx.x;
  const int cgi = bid & 31;
  const int dgb = bid >> 5;
  const int dg = dgb % DG;
  const int b = dgb / DG;
  const int d0 = dg * 64, l0 = cgi * 64;

  const int w = t >> 6, lane = t & 63;
  const int c = cgi * CPB + w;
  const int d = d0 + lane;
  const int row16 = t >> 4;
  const int col4 = (t & 15) * 4;

  // stage delta + B + C
#pragma unroll
  for (int rr = 0; rr < 4; rr++) {
    int row = row16 + rr * 16;
    long gof = ((long)(b * DIM + d0 + row)) * L + l0 + col4;
    *(float4*)&slab[row][col4] = *(const float4*)(delta + gof);
  }
  {
    long bof = ((long)(b * N + row16)) * L + l0 + col4;
    float4 v = *(const float4*)(Bg + bof);
    Bsr[col4 + 0][row16] = v.x;
    Bsr[col4 + 1][row16] = v.y;
    Bsr[col4 + 2][row16] = v.z;
    Bsr[col4 + 3][row16] = v.w;
    float4 wv = *(const float4*)(Cg + bof);
    Csr[col4 + 0][row16] = wv.x;
    Csr[col4 + 1][row16] = wv.y;
    Csr[col4 + 2][row16] = wv.z;
    Csr[col4 + 3][row16] = wv.w;
  }

  float A2[N];
#pragma unroll
  for (int q = 0; q < 4; q++) {
    float4 av = *(const float4*)(A + d * N + q * 4);
    A2[q*4+0] = av.x * LOG2E; A2[q*4+1] = av.y * LOG2E;
    A2[q*4+2] = av.z * LOG2E; A2[q*4+3] = av.w * LOG2E;
  }
  const float bias = dbias[d];

  // x_init: [b][c][d][n] -> 4x float4 contiguous
  const long hb = (((long)(b * NC + c)) * DIM + d) * N;
  float x[N];
#pragma unroll
  for (int q = 0; q < 4; q++) {
    float4 v = *(const float4*)(xinit + hb + q * 4);
    x[q*4+0] = v.x; x[q*4+1] = v.y; x[q*4+2] = v.z; x[q*4+3] = v.w;
  }

  __syncthreads();

  float sp[LC];
#pragma unroll
  for (int q = 0; q < 4; q++) {
    float4 dv = *(const float4*)&slab[lane][w * LC + q * 4];
    sp[q*4+0] = softplus(dv.x + bias);
    sp[q*4+1] = softplus(dv.y + bias);
    sp[q*4+2] = softplus(dv.z + bias);
    sp[q*4+3] = softplus(dv.w + bias);
  }

  __syncthreads();   // done reading slab-as-delta

  // restage u
#pragma unroll
  for (int rr = 0; rr < 4; rr++) {
    int row = row16 + rr * 16;
    long gof = ((long)(b * DIM + d0 + row)) * L + l0 + col4;
    *(float4*)&slab[row][col4] = *(const float4*)(u + gof);
  }

  __syncthreads();

  float uu[LC];
#pragma unroll
  for (int q = 0; q < 4; q++) {
    float4 uv = *(const float4*)&slab[lane][w * LC + q * 4];
    uu[q*4+0] = uv.x; uu[q*4+1] = uv.y; uu[q*4+2] = uv.z; uu[q*4+3] = uv.w;
  }

  float y[LC];
#pragma unroll
  for (int j = 0; j < LC; j++) {
    const int row = w * LC + j;
    float bb[16], ccv[16];
#pragma unroll
    for (int q = 0; q < 4; q++) {
      float4 bv = *(const float4*)&Bsr[row][q * 4];
      float4 cv = *(const float4*)&Csr[row][q * 4];
      bb[q*4+0] = bv.x; bb[q*4+1] = bv.y; bb[q*4+2] = bv.z; bb[q*4+3] = bv.w;
      ccv[q*4+0] = cv.x; ccv[q*4+1] = cv.y; ccv[q*4+2] = cv.z; ccv[q*4+3] = cv.w;
    }
    float du = sp[j] * uu[j];
    float acc = 0.f;
#pragma unroll
    for (int n = 0; n < N; n++) {
      float a = fexp2(sp[j] * A2[n]);
      x[n] = a * x[n] + du * bb[n];
      acc += x[n] * ccv[n];
    }
    y[j] = acc;
  }

  // write y into own cells (read only by this thread so far) -- no sync needed
#pragma unroll
  for (int q = 0; q < 4; q++) {
    float4 v; v.x = y[q*4+0]; v.y = y[q*4+1]; v.z = y[q*4+2]; v.w = y[q*4+3];
    *(float4*)&slab[lane][w * LC + q * 4] = v;
  }

  __syncthreads();

  // coalesced fused epilogue: out = (y + u*D) * silu(z); u re-read (L2-hot)
#pragma unroll
  for (int rr = 0; rr < 4; rr++) {
    int row = row16 + rr * 16;
    long gof = ((long)(b * DIM + d0 + row)) * L + l0 + col4;
    float4 zv = *(const float4*)(z + gof);
    float4 uv = *(const float4*)(u + gof);
    float4 yv = *(const float4*)&slab[row][col4];
    float Dd2 = Dv[d0 + row];
    float4 ov;
    ov.x = (yv.x + uv.x * Dd2) * silu(zv.x);
    ov.y = (yv.y + uv.y * Dd2) * silu(zv.y);
    ov.z = (yv.z + uv.z * Dd2) * silu(zv.z);
    ov.w = (yv.w + uv.w * Dd2) * silu(zv.w);
    *(float4*)(out + gof) = ov;
  }
}

// ---------------- fallback (ws too small) ----------------
__global__ __launch_bounds__(256) void k_simple(
    const float* __restrict__ u, const float* __restrict__ delta,
    const float* __restrict__ A, const float* __restrict__ dbias,
    const float* __restrict__ Bm, const float* __restrict__ Cm,
    const float* __restrict__ Dv, const float* __restrict__ z,
    float* __restrict__ out) {
  int t = blockIdx.x * 256 + threadIdx.x;
  int n = t % N;
  int bd = t / N;
  int d = bd % DIM;
  int b = bd / DIM;
  float A2 = A[d * N + n] * LOG2E;
  float bias = dbias[d];
  float Dd = Dv[d];
  const float* Bp = Bm + ((long)b * N + n) * L;
  const float* Cp = Cm + ((long)b * N + n) * L;
  long base = (long)bd * L;
  float x = 0.0f;
  for (int l = 0; l < L; l++) {
    float dv = delta[base + l];
    float uv = u[base + l];
    float sp = softplus(dv + bias);
    float a = fexp2(sp * A2);
    x = a * x + sp * uv * Bp[l];
    float y = x * Cp[l];
#pragma unroll
    for (int off = 8; off; off >>= 1) y += __shfl_xor(y, off, 16);
    if (n == 0) {
      float zv = z[base + l];
      out[base + l] = (y + uv * Dd) * silu(zv);
    }
  }
}

extern "C" void kernel_launch(void* const* d_in, const int* in_sizes, int n_in,
                              void* d_out, int out_size, void* d_ws, size_t ws_size,
                              hipStream_t stream) {
  const float* u     = (const float*)d_in[0];
  const float* delta = (const float*)d_in[1];
  const float* A     = (const float*)d_in[2];
  const float* Bm    = (const float*)d_in[3];
  const float* Cm    = (const float*)d_in[4];
  const float* Dv    = (const float*)d_in[5];
  const float* z     = (const float*)d_in[6];
  const float* dbias = (const float*)d_in[7];
  float* out = (float*)d_out;

  const size_t hp  = (size_t)BATCH * NC * DIM * N;  // 3.15M floats
  const size_t spn = (size_t)BATCH * NC * DIM;      // 196K floats
  const size_t need = (2 * hp + spn) * sizeof(float);

  if (ws_size < need) {
    k_simple<<<(BATCH * DIM * N) / 256, 256, 0, stream>>>(u, delta, A, dbias, Bm, Cm, Dv, z, out);
    return;
  }

  float* h  = (float*)d_ws;
  float* S  = h + hp;
  float* hI = S + spn;

  k_pass1<<<NBLK, 256, 0, stream>>>(u, delta, A, dbias, Bm, h, S);
  k_pass2<<<NCOMB / 128, 128, 0, stream>>>(h, S, A, hI);
  k_pass3<<<NBLK, 256, 0, stream>>>(u, delta, A, dbias, Bm, Cm, Dv, z, hI, out);
}

// Round 10
// 131.151 us; speedup vs baseline: 1.9352x; 1.0112x over previous
//
#include <hip/hip_runtime.h>

// Mamba selective scan: BATCH=2, DIM=768, L=2048, N=16, fp32.
// R10: bank-conflict fix round.
//  - Slab rows padded to 76 floats (76 mod 32 = 12): ds_read_b128 across 64
//    lanes tiles all 32 banks -> conflict-free (R7's 68 was 8-way conflicted,
//    2.2M conflict cycles in R8's PMC).
//  - Dual delta/u slabs, all global loads issued up front (R9's time-shared
//    slab serialized the two HBM reads - reverted).
//  - h/hI [b][c][d][n] float4 layout + non-aliased pass2 (kept from R8/R9).
//  - p3 prefetches z into registers before the scan (HBM latency hides).

#define LOG2E 1.4426950408889634f
#define LN2   0.6931471805599453f

constexpr int BATCH = 2, DIM = 768, L = 2048, N = 16;
constexpr int NC = 128, LC = 16;       // chunks, steps per chunk
constexpr int DG = DIM / 64;           // 12 d-groups
constexpr int CPB = 4;                 // chunks per block (1 per wave)
constexpr int CG = NC / CPB;           // 32 chunk-groups
constexpr int NBLK = BATCH * DG * CG;  // 768 blocks
constexpr int NCOMB = BATCH * DIM * N; // 24576 combine threads
constexpr int PAD = 76;                // row stride: 76 % 32 == 12 -> b128 conflict-free
static_assert(NC * LC == L, "chunking must cover L");

__device__ __forceinline__ float fexp2(float x) { return __builtin_amdgcn_exp2f(x); }
__device__ __forceinline__ float softplus(float v) {
  float s = LN2 * __log2f(1.0f + fexp2(v * LOG2E));
  return (v > 20.0f) ? v : s;
}
__device__ __forceinline__ float silu(float v) { return v / (1.0f + fexp2(-v * LOG2E)); }

// ---------------- pass 1 ----------------
__global__ __launch_bounds__(256, 3) void k_pass1(
    const float* __restrict__ u, const float* __restrict__ delta,
    const float* __restrict__ A, const float* __restrict__ dbias,
    const float* __restrict__ Bg, float* __restrict__ h, float* __restrict__ S)
{
  __shared__ float ds_[64][PAD];
  __shared__ float us[64][PAD];
  __shared__ float Bsr[64][20];    // [l][n] transposed

  const int bid = blockIdx.x, t = threadIdx.x;
  const int cgi = bid & 31;
  const int dgb = bid >> 5;
  const int dg = dgb % DG;
  const int b = dgb / DG;
  const int d0 = dg * 64, l0 = cgi * 64;

  const int w = t >> 6, lane = t & 63;
  const int c = cgi * CPB + w;
  const int d = d0 + lane;
  const int row16 = t >> 4;
  const int col4 = (t & 15) * 4;

  // issue ALL global loads up front (max MLP), then write LDS
  float4 dreg[4], ureg[4];
#pragma unroll
  for (int rr = 0; rr < 4; rr++) {
    int row = row16 + rr * 16;
    long gof = ((long)(b * DIM + d0 + row)) * L + l0 + col4;
    dreg[rr] = *(const float4*)(delta + gof);
    ureg[rr] = *(const float4*)(u + gof);
  }
  long bof = ((long)(b * N + row16)) * L + l0 + col4;
  float4 breg = *(const float4*)(Bg + bof);

  float A2[N];
#pragma unroll
  for (int q = 0; q < 4; q++) {
    float4 av = *(const float4*)(A + d * N + q * 4);
    A2[q*4+0] = av.x * LOG2E; A2[q*4+1] = av.y * LOG2E;
    A2[q*4+2] = av.z * LOG2E; A2[q*4+3] = av.w * LOG2E;
  }
  const float bias = dbias[d];

#pragma unroll
  for (int rr = 0; rr < 4; rr++) {
    int row = row16 + rr * 16;
    *(float4*)&ds_[row][col4] = dreg[rr];
    *(float4*)&us[row][col4]  = ureg[rr];
  }
  Bsr[col4 + 0][row16] = breg.x;
  Bsr[col4 + 1][row16] = breg.y;
  Bsr[col4 + 2][row16] = breg.z;
  Bsr[col4 + 3][row16] = breg.w;

  __syncthreads();

  float sp[LC], uu[LC], Ssum = 0.f;
#pragma unroll
  for (int q = 0; q < 4; q++) {
    float4 dv = *(const float4*)&ds_[lane][w * LC + q * 4];
    float4 uv = *(const float4*)&us[lane][w * LC + q * 4];
    sp[q*4+0] = softplus(dv.x + bias); uu[q*4+0] = uv.x;
    sp[q*4+1] = softplus(dv.y + bias); uu[q*4+1] = uv.y;
    sp[q*4+2] = softplus(dv.z + bias); uu[q*4+2] = uv.z;
    sp[q*4+3] = softplus(dv.w + bias); uu[q*4+3] = uv.w;
  }
#pragma unroll
  for (int j = 0; j < LC; j++) Ssum += sp[j];

  float x[N];
#pragma unroll
  for (int n = 0; n < N; n++) x[n] = 0.f;
#pragma unroll
  for (int j = 0; j < LC; j++) {
    const int row = w * LC + j;
    float bb[16];
#pragma unroll
    for (int q = 0; q < 4; q++) {
      float4 bv = *(const float4*)&Bsr[row][q * 4];   // broadcast b128
      bb[q*4+0] = bv.x; bb[q*4+1] = bv.y; bb[q*4+2] = bv.z; bb[q*4+3] = bv.w;
    }
    float du = sp[j] * uu[j];
#pragma unroll
    for (int n = 0; n < N; n++) {
      float a = fexp2(sp[j] * A2[n]);
      x[n] = a * x[n] + du * bb[n];
    }
  }

  // h [b][c][d][n]: 4x float4 contiguous per lane
  const long hb = (((long)(b * NC + c)) * DIM + d) * N;
#pragma unroll
  for (int q = 0; q < 4; q++) {
    float4 v; v.x = x[q*4+0]; v.y = x[q*4+1]; v.z = x[q*4+2]; v.w = x[q*4+3];
    *(float4*)(h + hb + q * 4) = v;
  }
  S[(b * NC + c) * DIM + d] = Ssum;
}

// ---------------- pass 2: combine, no alias, batched ----------------
__global__ __launch_bounds__(128) void k_pass2(
    const float* __restrict__ h, const float* __restrict__ S,
    const float* __restrict__ A, float* __restrict__ hI)
{
  int g = blockIdx.x * 128 + threadIdx.x;   // g = (bb*768 + dd)*16 + n
  int n = g & 15;
  int r = g >> 4;
  int dd = r % DIM;
  int bb = r / DIM;
  const float a2 = A[dd * N + n] * LOG2E;
  const long step = (long)DIM * N;
  const long base0 = (((long)bb * NC) * DIM + dd) * N + n;
  const long sbase = (long)(bb * NC) * DIM + dd;

  float x = 0.f;
  for (int cb = 0; cb < NC / 16; cb++) {
    float hc[16], Sc[16];
#pragma unroll
    for (int k = 0; k < 16; k++) {
      hc[k] = h[base0 + (long)(cb * 16 + k) * step];
      Sc[k] = S[sbase + (long)(cb * 16 + k) * DIM];
    }
#pragma unroll
    for (int k = 0; k < 16; k++) {
      hI[base0 + (long)(cb * 16 + k) * step] = x;
      x = fexp2(Sc[k] * a2) * x + hc[k];
    }
  }
}

// ---------------- pass 3 ----------------
__global__ __launch_bounds__(256, 3) void k_pass3(
    const float* __restrict__ u, const float* __restrict__ delta,
    const float* __restrict__ A, const float* __restrict__ dbias,
    const float* __restrict__ Bg, const float* __restrict__ Cg,
    const float* __restrict__ Dv, const float* __restrict__ z,
    const float* __restrict__ xinit, float* __restrict__ out)
{
  __shared__ float ds_[64][PAD];   // delta slab, reused as y slab
  __shared__ float us[64][PAD];
  __shared__ float Bsr[64][20];
  __shared__ float Csr[64][20];

  const int bid = blockIdx.x, t = threadIdx.x;
  const int cgi = bid & 31;
  const int dgb = bid >> 5;
  const int dg = dgb % DG;
  const int b = dgb / DG;
  const int d0 = dg * 64, l0 = cgi * 64;

  const int w = t >> 6, lane = t & 63;
  const int c = cgi * CPB + w;
  const int d = d0 + lane;
  const int row16 = t >> 4;
  const int col4 = (t & 15) * 4;

  // issue ALL global loads up front
  float4 dreg[4], ureg[4], zreg[4];
#pragma unroll
  for (int rr = 0; rr < 4; rr++) {
    int row = row16 + rr * 16;
    long gof = ((long)(b * DIM + d0 + row)) * L + l0 + col4;
    dreg[rr] = *(const float4*)(delta + gof);
    ureg[rr] = *(const float4*)(u + gof);
    zreg[rr] = *(const float4*)(z + gof);     // prefetch; consumed in epilogue
  }
  long bof = ((long)(b * N + row16)) * L + l0 + col4;
  float4 breg = *(const float4*)(Bg + bof);
  float4 creg = *(const float4*)(Cg + bof);

  // x_init: [b][c][d][n] -> 4x float4 contiguous
  const long hb = (((long)(b * NC + c)) * DIM + d) * N;
  float x[N];
#pragma unroll
  for (int q = 0; q < 4; q++) {
    float4 v = *(const float4*)(xinit + hb + q * 4);
    x[q*4+0] = v.x; x[q*4+1] = v.y; x[q*4+2] = v.z; x[q*4+3] = v.w;
  }

  float A2[N];
#pragma unroll
  for (int q = 0; q < 4; q++) {
    float4 av = *(const float4*)(A + d * N + q * 4);
    A2[q*4+0] = av.x * LOG2E; A2[q*4+1] = av.y * LOG2E;
    A2[q*4+2] = av.z * LOG2E; A2[q*4+3] = av.w * LOG2E;
  }
  const float bias = dbias[d];

#pragma unroll
  for (int rr = 0; rr < 4; rr++) {
    int row = row16 + rr * 16;
    *(float4*)&ds_[row][col4] = dreg[rr];
    *(float4*)&us[row][col4]  = ureg[rr];
  }
  Bsr[col4 + 0][row16] = breg.x;
  Bsr[col4 + 1][row16] = breg.y;
  Bsr[col4 + 2][row16] = breg.z;
  Bsr[col4 + 3][row16] = breg.w;
  Csr[col4 + 0][row16] = creg.x;
  Csr[col4 + 1][row16] = creg.y;
  Csr[col4 + 2][row16] = creg.z;
  Csr[col4 + 3][row16] = creg.w;

  __syncthreads();

  float sp[LC], uu[LC];
#pragma unroll
  for (int q = 0; q < 4; q++) {
    float4 dv = *(const float4*)&ds_[lane][w * LC + q * 4];
    float4 uv = *(const float4*)&us[lane][w * LC + q * 4];
    sp[q*4+0] = softplus(dv.x + bias); uu[q*4+0] = uv.x;
    sp[q*4+1] = softplus(dv.y + bias); uu[q*4+1] = uv.y;
    sp[q*4+2] = softplus(dv.z + bias); uu[q*4+2] = uv.z;
    sp[q*4+3] = softplus(dv.w + bias); uu[q*4+3] = uv.w;
  }

  float y[LC];
#pragma unroll
  for (int j = 0; j < LC; j++) {
    const int row = w * LC + j;
    float bb[16], ccv[16];
#pragma unroll
    for (int q = 0; q < 4; q++) {
      float4 bv = *(const float4*)&Bsr[row][q * 4];   // broadcast b128
      float4 cv = *(const float4*)&Csr[row][q * 4];
      bb[q*4+0] = bv.x; bb[q*4+1] = bv.y; bb[q*4+2] = bv.z; bb[q*4+3] = bv.w;
      ccv[q*4+0] = cv.x; ccv[q*4+1] = cv.y; ccv[q*4+2] = cv.z; ccv[q*4+3] = cv.w;
    }
    float du = sp[j] * uu[j];
    float acc = 0.f;
#pragma unroll
    for (int n = 0; n < N; n++) {
      float a = fexp2(sp[j] * A2[n]);
      x[n] = a * x[n] + du * bb[n];
      acc += x[n] * ccv[n];
    }
    y[j] = acc;
  }

  __syncthreads();   // all waves done reading ds_ as delta
#pragma unroll
  for (int q = 0; q < 4; q++) {
    float4 v; v.x = y[q*4+0]; v.y = y[q*4+1]; v.z = y[q*4+2]; v.w = y[q*4+3];
    *(float4*)&ds_[lane][w * LC + q * 4] = v;
  }

  __syncthreads();

  // coalesced fused epilogue: out = (y + u*D) * silu(z); u from LDS, z from regs
#pragma unroll
  for (int rr = 0; rr < 4; rr++) {
    int row = row16 + rr * 16;
    long gof = ((long)(b * DIM + d0 + row)) * L + l0 + col4;
    float4 zv = zreg[rr];
    float4 yv = *(const float4*)&ds_[row][col4];
    float4 uv = *(const float4*)&us[row][col4];
    float Dd2 = Dv[d0 + row];
    float4 ov;
    ov.x = (yv.x + uv.x * Dd2) * silu(zv.x);
    ov.y = (yv.y + uv.y * Dd2) * silu(zv.y);
    ov.z = (yv.z + uv.z * Dd2) * silu(zv.z);
    ov.w = (yv.w + uv.w * Dd2) * silu(zv.w);
    *(float4*)(out + gof) = ov;
  }
}

// ---------------- fallback (ws too small) ----------------
__global__ __launch_bounds__(256) void k_simple(
    const float* __restrict__ u, const float* __restrict__ delta,
    const float* __restrict__ A, const float* __restrict__ dbias,
    const float* __restrict__ Bm, const float* __restrict__ Cm,
    const float* __restrict__ Dv, const float* __restrict__ z,
    float* __restrict__ out) {
  int t = blockIdx.x * 256 + threadIdx.x;
  int n = t % N;
  int bd = t / N;
  int d = bd % DIM;
  int b = bd / DIM;
  float A2 = A[d * N + n] * LOG2E;
  float bias = dbias[d];
  float Dd = Dv[d];
  const float* Bp = Bm + ((long)b * N + n) * L;
  const float* Cp = Cm + ((long)b * N + n) * L;
  long base = (long)bd * L;
  float x = 0.0f;
  for (int l = 0; l < L; l++) {
    float dv = delta[base + l];
    float uv = u[base + l];
    float sp = softplus(dv + bias);
    float a = fexp2(sp * A2);
    x = a * x + sp * uv * Bp[l];
    float y = x * Cp[l];
#pragma unroll
    for (int off = 8; off; off >>= 1) y += __shfl_xor(y, off, 16);
    if (n == 0) {
      float zv = z[base + l];
      out[base + l] = (y + uv * Dd) * silu(zv);
    }
  }
}

extern "C" void kernel_launch(void* const* d_in, const int* in_sizes, int n_in,
                              void* d_out, int out_size, void* d_ws, size_t ws_size,
                              hipStream_t stream) {
  const float* u     = (const float*)d_in[0];
  const float* delta = (const float*)d_in[1];
  const float* A     = (const float*)d_in[2];
  const float* Bm    = (const float*)d_in[3];
  const float* Cm    = (const float*)d_in[4];
  const float* Dv    = (const float*)d_in[5];
  const float* z     = (const float*)d_in[6];
  const float* dbias = (const float*)d_in[7];
  float* out = (float*)d_out;

  const size_t hp  = (size_t)BATCH * NC * DIM * N;  // 3.15M floats
  const size_t spn = (size_t)BATCH * NC * DIM;      // 196K floats
  const size_t need = (2 * hp + spn) * sizeof(float);

  if (ws_size < need) {
    k_simple<<<(BATCH * DIM * N) / 256, 256, 0, stream>>>(u, delta, A, dbias, Bm, Cm, Dv, z, out);
    return;
  }

  float* h  = (float*)d_ws;
  float* S  = h + hp;
  float* hI = S + spn;

  k_pass1<<<NBLK, 256, 0, stream>>>(u, delta, A, dbias, Bm, h, S);
  k_pass2<<<NCOMB / 128, 128, 0, stream>>>(h, S, A, hI);
  k_pass3<<<NBLK, 256, 0, stream>>>(u, delta, A, dbias, Bm, Cm, Dv, z, hI, out);
}

// Round 11
// 129.684 us; speedup vs baseline: 1.9571x; 1.0113x over previous
//
#include <hip/hip_runtime.h>

// Mamba selective scan: BATCH=2, DIM=768, L=2048, N=16, fp32.
// R11: occupancy round — drop the u LDS slab (u per-lane rows are single
// full cache lines: 64B/lane, zero overfetch, latency-hideable), keeping
// only delta transposed in LDS. p1: 24.6KB -> 6 blk/CU; p3: 40KB -> 4 blk/CU.
// Epilogue re-reads u coalesced (L2-hot). Everything else = R10.

#define LOG2E 1.4426950408889634f
#define LN2   0.6931471805599453f

constexpr int BATCH = 2, DIM = 768, L = 2048, N = 16;
constexpr int NC = 128, LC = 16;       // chunks, steps per chunk
constexpr int DG = DIM / 64;           // 12 d-groups
constexpr int CPB = 4;                 // chunks per block (1 per wave)
constexpr int CG = NC / CPB;           // 32 chunk-groups
constexpr int NBLK = BATCH * DG * CG;  // 768 blocks
constexpr int NCOMB = BATCH * DIM * N; // 24576 combine threads
constexpr int PAD = 76;                // 76 % 32 == 12 -> b128 reads hit the 8-word/bank floor
static_assert(NC * LC == L, "chunking must cover L");

__device__ __forceinline__ float fexp2(float x) { return __builtin_amdgcn_exp2f(x); }
__device__ __forceinline__ float softplus(float v) {
  float s = LN2 * __log2f(1.0f + fexp2(v * LOG2E));
  return (v > 20.0f) ? v : s;
}
__device__ __forceinline__ float silu(float v) { return v / (1.0f + fexp2(-v * LOG2E)); }

// ---------------- pass 1 ----------------
__global__ __launch_bounds__(256, 6) void k_pass1(
    const float* __restrict__ u, const float* __restrict__ delta,
    const float* __restrict__ A, const float* __restrict__ dbias,
    const float* __restrict__ Bg, float* __restrict__ h, float* __restrict__ S)
{
  __shared__ float ds_[64][PAD];   // delta, [d][l] transposed
  __shared__ float Bsr[64][20];    // B, [l][n] transposed

  const int bid = blockIdx.x, t = threadIdx.x;
  const int cgi = bid & 31;
  const int dgb = bid >> 5;
  const int dg = dgb % DG;
  const int b = dgb / DG;
  const int d0 = dg * 64, l0 = cgi * 64;

  const int w = t >> 6, lane = t & 63;
  const int c = cgi * CPB + w;
  const int d = d0 + lane;
  const int row16 = t >> 4;
  const int col4 = (t & 15) * 4;

  // u: per-lane direct — this lane's chunk row is 64B contiguous (1 line)
  const long ubase = ((long)(b * DIM + d)) * L + c * LC;
  float4 u0 = *(const float4*)(u + ubase + 0);
  float4 u1 = *(const float4*)(u + ubase + 4);
  float4 u2 = *(const float4*)(u + ubase + 8);
  float4 u3 = *(const float4*)(u + ubase + 12);

  // delta + B: coalesced staging
  float4 dreg[4];
#pragma unroll
  for (int rr = 0; rr < 4; rr++) {
    int row = row16 + rr * 16;
    long gof = ((long)(b * DIM + d0 + row)) * L + l0 + col4;
    dreg[rr] = *(const float4*)(delta + gof);
  }
  long bof = ((long)(b * N + row16)) * L + l0 + col4;
  float4 breg = *(const float4*)(Bg + bof);

  float A2[N];
#pragma unroll
  for (int q = 0; q < 4; q++) {
    float4 av = *(const float4*)(A + d * N + q * 4);
    A2[q*4+0] = av.x * LOG2E; A2[q*4+1] = av.y * LOG2E;
    A2[q*4+2] = av.z * LOG2E; A2[q*4+3] = av.w * LOG2E;
  }
  const float bias = dbias[d];

#pragma unroll
  for (int rr = 0; rr < 4; rr++) {
    int row = row16 + rr * 16;
    *(float4*)&ds_[row][col4] = dreg[rr];
  }
  Bsr[col4 + 0][row16] = breg.x;
  Bsr[col4 + 1][row16] = breg.y;
  Bsr[col4 + 2][row16] = breg.z;
  Bsr[col4 + 3][row16] = breg.w;

  float uu[LC];
  uu[0]=u0.x; uu[1]=u0.y; uu[2]=u0.z; uu[3]=u0.w;
  uu[4]=u1.x; uu[5]=u1.y; uu[6]=u1.z; uu[7]=u1.w;
  uu[8]=u2.x; uu[9]=u2.y; uu[10]=u2.z; uu[11]=u2.w;
  uu[12]=u3.x; uu[13]=u3.y; uu[14]=u3.z; uu[15]=u3.w;

  __syncthreads();

  float sp[LC], Ssum = 0.f;
#pragma unroll
  for (int q = 0; q < 4; q++) {
    float4 dv = *(const float4*)&ds_[lane][w * LC + q * 4];
    sp[q*4+0] = softplus(dv.x + bias);
    sp[q*4+1] = softplus(dv.y + bias);
    sp[q*4+2] = softplus(dv.z + bias);
    sp[q*4+3] = softplus(dv.w + bias);
  }
#pragma unroll
  for (int j = 0; j < LC; j++) Ssum += sp[j];

  float x[N];
#pragma unroll
  for (int n = 0; n < N; n++) x[n] = 0.f;
#pragma unroll
  for (int j = 0; j < LC; j++) {
    const int row = w * LC + j;
    float bb[16];
#pragma unroll
    for (int q = 0; q < 4; q++) {
      float4 bv = *(const float4*)&Bsr[row][q * 4];   // broadcast b128
      bb[q*4+0] = bv.x; bb[q*4+1] = bv.y; bb[q*4+2] = bv.z; bb[q*4+3] = bv.w;
    }
    float du = sp[j] * uu[j];
#pragma unroll
    for (int n = 0; n < N; n++) {
      float a = fexp2(sp[j] * A2[n]);
      x[n] = a * x[n] + du * bb[n];
    }
  }

  // h [b][c][d][n]: 4x float4 contiguous per lane
  const long hb = (((long)(b * NC + c)) * DIM + d) * N;
#pragma unroll
  for (int q = 0; q < 4; q++) {
    float4 v; v.x = x[q*4+0]; v.y = x[q*4+1]; v.z = x[q*4+2]; v.w = x[q*4+3];
    *(float4*)(h + hb + q * 4) = v;
  }
  S[(b * NC + c) * DIM + d] = Ssum;
}

// ---------------- pass 2: combine, no alias, batched ----------------
__global__ __launch_bounds__(128) void k_pass2(
    const float* __restrict__ h, const float* __restrict__ S,
    const float* __restrict__ A, float* __restrict__ hI)
{
  int g = blockIdx.x * 128 + threadIdx.x;   // g = (bb*768 + dd)*16 + n
  int n = g & 15;
  int r = g >> 4;
  int dd = r % DIM;
  int bb = r / DIM;
  const float a2 = A[dd * N + n] * LOG2E;
  const long step = (long)DIM * N;
  const long base0 = (((long)bb * NC) * DIM + dd) * N + n;
  const long sbase = (long)(bb * NC) * DIM + dd;

  float x = 0.f;
  for (int cb = 0; cb < NC / 16; cb++) {
    float hc[16], Sc[16];
#pragma unroll
    for (int k = 0; k < 16; k++) {
      hc[k] = h[base0 + (long)(cb * 16 + k) * step];
      Sc[k] = S[sbase + (long)(cb * 16 + k) * DIM];
    }
#pragma unroll
    for (int k = 0; k < 16; k++) {
      hI[base0 + (long)(cb * 16 + k) * step] = x;
      x = fexp2(Sc[k] * a2) * x + hc[k];
    }
  }
}

// ---------------- pass 3 ----------------
__global__ __launch_bounds__(256, 4) void k_pass3(
    const float* __restrict__ u, const float* __restrict__ delta,
    const float* __restrict__ A, const float* __restrict__ dbias,
    const float* __restrict__ Bg, const float* __restrict__ Cg,
    const float* __restrict__ Dv, const float* __restrict__ z,
    const float* __restrict__ xinit, float* __restrict__ out)
{
  __shared__ float ds_[64][PAD];   // delta slab, reused as y slab
  __shared__ float Bsr[64][20];
  __shared__ float Csr[64][20];

  const int bid = blockIdx.x, t = threadIdx.x;
  const int cgi = bid & 31;
  const int dgb = bid >> 5;
  const int dg = dgb % DG;
  const int b = dgb / DG;
  const int d0 = dg * 64, l0 = cgi * 64;

  const int w = t >> 6, lane = t & 63;
  const int c = cgi * CPB + w;
  const int d = d0 + lane;
  const int row16 = t >> 4;
  const int col4 = (t & 15) * 4;

  // u per-lane direct (one 64B line per lane)
  const long ubase = ((long)(b * DIM + d)) * L + c * LC;
  float4 u0 = *(const float4*)(u + ubase + 0);
  float4 u1 = *(const float4*)(u + ubase + 4);
  float4 u2 = *(const float4*)(u + ubase + 8);
  float4 u3 = *(const float4*)(u + ubase + 12);

  // delta + B + C + z: coalesced
  float4 dreg[4], zreg[4];
#pragma unroll
  for (int rr = 0; rr < 4; rr++) {
    int row = row16 + rr * 16;
    long gof = ((long)(b * DIM + d0 + row)) * L + l0 + col4;
    dreg[rr] = *(const float4*)(delta + gof);
    zreg[rr] = *(const float4*)(z + gof);
  }
  long bof = ((long)(b * N + row16)) * L + l0 + col4;
  float4 breg = *(const float4*)(Bg + bof);
  float4 creg = *(const float4*)(Cg + bof);

  // x_init: [b][c][d][n] -> 4x float4 contiguous
  const long hb = (((long)(b * NC + c)) * DIM + d) * N;
  float x[N];
#pragma unroll
  for (int q = 0; q < 4; q++) {
    float4 v = *(const float4*)(xinit + hb + q * 4);
    x[q*4+0] = v.x; x[q*4+1] = v.y; x[q*4+2] = v.z; x[q*4+3] = v.w;
  }

  float A2[N];
#pragma unroll
  for (int q = 0; q < 4; q++) {
    float4 av = *(const float4*)(A + d * N + q * 4);
    A2[q*4+0] = av.x * LOG2E; A2[q*4+1] = av.y * LOG2E;
    A2[q*4+2] = av.z * LOG2E; A2[q*4+3] = av.w * LOG2E;
  }
  const float bias = dbias[d];

#pragma unroll
  for (int rr = 0; rr < 4; rr++) {
    int row = row16 + rr * 16;
    *(float4*)&ds_[row][col4] = dreg[rr];
  }
  Bsr[col4 + 0][row16] = breg.x;
  Bsr[col4 + 1][row16] = breg.y;
  Bsr[col4 + 2][row16] = breg.z;
  Bsr[col4 + 3][row16] = breg.w;
  Csr[col4 + 0][row16] = creg.x;
  Csr[col4 + 1][row16] = creg.y;
  Csr[col4 + 2][row16] = creg.z;
  Csr[col4 + 3][row16] = creg.w;

  float uu[LC];
  uu[0]=u0.x; uu[1]=u0.y; uu[2]=u0.z; uu[3]=u0.w;
  uu[4]=u1.x; uu[5]=u1.y; uu[6]=u1.z; uu[7]=u1.w;
  uu[8]=u2.x; uu[9]=u2.y; uu[10]=u2.z; uu[11]=u2.w;
  uu[12]=u3.x; uu[13]=u3.y; uu[14]=u3.z; uu[15]=u3.w;

  __syncthreads();

  float sp[LC];
#pragma unroll
  for (int q = 0; q < 4; q++) {
    float4 dv = *(const float4*)&ds_[lane][w * LC + q * 4];
    sp[q*4+0] = softplus(dv.x + bias);
    sp[q*4+1] = softplus(dv.y + bias);
    sp[q*4+2] = softplus(dv.z + bias);
    sp[q*4+3] = softplus(dv.w + bias);
  }

  float y[LC];
#pragma unroll
  for (int j = 0; j < LC; j++) {
    const int row = w * LC + j;
    float bb[16], ccv[16];
#pragma unroll
    for (int q = 0; q < 4; q++) {
      float4 bv = *(const float4*)&Bsr[row][q * 4];   // broadcast b128
      float4 cv = *(const float4*)&Csr[row][q * 4];
      bb[q*4+0] = bv.x; bb[q*4+1] = bv.y; bb[q*4+2] = bv.z; bb[q*4+3] = bv.w;
      ccv[q*4+0] = cv.x; ccv[q*4+1] = cv.y; ccv[q*4+2] = cv.z; ccv[q*4+3] = cv.w;
    }
    float du = sp[j] * uu[j];
    float acc = 0.f;
#pragma unroll
    for (int n = 0; n < N; n++) {
      float a = fexp2(sp[j] * A2[n]);
      x[n] = a * x[n] + du * bb[n];
      acc += x[n] * ccv[n];
    }
    y[j] = acc;
  }

  __syncthreads();   // all waves done reading ds_ as delta
#pragma unroll
  for (int q = 0; q < 4; q++) {
    float4 v; v.x = y[q*4+0]; v.y = y[q*4+1]; v.z = y[q*4+2]; v.w = y[q*4+3];
    *(float4*)&ds_[lane][w * LC + q * 4] = v;
  }

  __syncthreads();

  // coalesced epilogue: out = (y + u*D) * silu(z); u re-read (L1/L2-hot)
#pragma unroll
  for (int rr = 0; rr < 4; rr++) {
    int row = row16 + rr * 16;
    long gof = ((long)(b * DIM + d0 + row)) * L + l0 + col4;
    float4 zv = zreg[rr];
    float4 uv = *(const float4*)(u + gof);
    float4 yv = *(const float4*)&ds_[row][col4];
    float Dd2 = Dv[d0 + row];
    float4 ov;
    ov.x = (yv.x + uv.x * Dd2) * silu(zv.x);
    ov.y = (yv.y + uv.y * Dd2) * silu(zv.y);
    ov.z = (yv.z + uv.z * Dd2) * silu(zv.z);
    ov.w = (yv.w + uv.w * Dd2) * silu(zv.w);
    *(float4*)(out + gof) = ov;
  }
}

// ---------------- fallback (ws too small) ----------------
__global__ __launch_bounds__(256) void k_simple(
    const float* __restrict__ u, const float* __restrict__ delta,
    const float* __restrict__ A, const float* __restrict__ dbias,
    const float* __restrict__ Bm, const float* __restrict__ Cm,
    const float* __restrict__ Dv, const float* __restrict__ z,
    float* __restrict__ out) {
  int t = blockIdx.x * 256 + threadIdx.x;
  int n = t % N;
  int bd = t / N;
  int d = bd % DIM;
  int b = bd / DIM;
  float A2 = A[d * N + n] * LOG2E;
  float bias = dbias[d];
  float Dd = Dv[d];
  const float* Bp = Bm + ((long)b * N + n) * L;
  const float* Cp = Cm + ((long)b * N + n) * L;
  long base = (long)bd * L;
  float x = 0.0f;
  for (int l = 0; l < L; l++) {
    float dv = delta[base + l];
    float uv = u[base + l];
    float sp = softplus(dv + bias);
    float a = fexp2(sp * A2);
    x = a * x + sp * uv * Bp[l];
    float y = x * Cp[l];
#pragma unroll
    for (int off = 8; off; off >>= 1) y += __shfl_xor(y, off, 16);
    if (n == 0) {
      float zv = z[base + l];
      out[base + l] = (y + uv * Dd) * silu(zv);
    }
  }
}

extern "C" void kernel_launch(void* const* d_in, const int* in_sizes, int n_in,
                              void* d_out, int out_size, void* d_ws, size_t ws_size,
                              hipStream_t stream) {
  const float* u     = (const float*)d_in[0];
  const float* delta = (const float*)d_in[1];
  const float* A     = (const float*)d_in[2];
  const float* Bm    = (const float*)d_in[3];
  const float* Cm    = (const float*)d_in[4];
  const float* Dv    = (const float*)d_in[5];
  const float* z     = (const float*)d_in[6];
  const float* dbias = (const float*)d_in[7];
  float* out = (float*)d_out;

  const size_t hp  = (size_t)BATCH * NC * DIM * N;  // 3.15M floats
  const size_t spn = (size_t)BATCH * NC * DIM;      // 196K floats
  const size_t need = (2 * hp + spn) * sizeof(float);

  if (ws_size < need) {
    k_simple<<<(BATCH * DIM * N) / 256, 256, 0, stream>>>(u, delta, A, dbias, Bm, Cm, Dv, z, out);
    return;
  }

  float* h  = (float*)d_ws;
  float* S  = h + hp;
  float* hI = S + spn;

  k_pass1<<<NBLK, 256, 0, stream>>>(u, delta, A, dbias, Bm, h, S);
  k_pass2<<<NCOMB / 128, 128, 0, stream>>>(h, S, A, hI);
  k_pass3<<<NBLK, 256, 0, stream>>>(u, delta, A, dbias, Bm, Cm, Dv, z, hI, out);
}